// Round 7
// baseline (3149.174 us; speedup 1.0000x reference)
//
#include <hip/hip_runtime.h>
#include <hip/hip_bf16.h>
#include <stdint.h>

typedef __attribute__((ext_vector_type(8))) short bf16x8;
typedef __attribute__((ext_vector_type(4))) float f32x4;

__device__ __forceinline__ float bf2f(unsigned short u){
  union { unsigned int i; float f; } v; v.i = ((unsigned int)u) << 16; return v.f;
}
__device__ __forceinline__ unsigned short f2bf(float f){
  union { float f; unsigned int i; } v; v.f = f;
  return (unsigned short)((v.i + 0x7FFFu + ((v.i >> 16) & 1u)) >> 16);
}

__device__ __forceinline__ void gload16(const void* g, void* l){
  __builtin_amdgcn_global_load_lds(
      (const __attribute__((address_space(1))) void*)g,
      (__attribute__((address_space(3))) void*)l, 16, 0, 0);
}

// per-head panel offsets inside R2 (in shorts)
#define VT_OFF 0L
#define Q_OFF  30720000L
#define K_OFF  60825600L

// ---------------- weight cast + transpose: W[K][N] f32 -> Wt[N][K] bf16 ----------------
__global__ __launch_bounds__(256) void k_castT(const float* __restrict__ W,
                                               unsigned short* __restrict__ Wt,
                                               int K, int N){
  __shared__ float tl[32][33];
  int ntn = N >> 5;
  int kt = blockIdx.x / ntn, nt = blockIdx.x % ntn;
  int r = threadIdx.x >> 5, c = threadIdx.x & 31;
#pragma unroll
  for (int rr = 0; rr < 4; rr++){
    int row = (kt << 5) + r + (rr << 3);
    tl[r + (rr << 3)][c] = W[(long)row * N + (nt << 5) + c];
  }
  __syncthreads();
#pragma unroll
  for (int rr = 0; rr < 4; rr++){
    int n = (nt << 5) + r + (rr << 3);
    int k = (kt << 5) + c;
    Wt[(long)n * K + k] = f2bf(tl[c][r + (rr << 3)]);
  }
}

// ---------------- LayerNorm fp32 -> bf16 ----------------
__global__ __launch_bounds__(256) void k_ln(const float* __restrict__ X,
                                            const float* __restrict__ w,
                                            const float* __restrict__ b,
                                            unsigned short* __restrict__ out,
                                            int mode){
  int p = blockIdx.x, t = threadIdx.x;
  unsigned short* orow = out + (long)p * 768;
  const float* xrow;
  if (mode == 1){
    int win = p / 196, tok = p - win * 196;
    int bb = win / 25, wrem = win - bb * 25;
    int wy = wrem / 5, wx = wrem - wy * 5;
    int ty = tok / 14, tx = tok - ty * 14;
    int yy = wy * 14 + ty, xx = wx * 14 + tx;
    if (yy >= 64 || xx >= 64){
      for (int j = t; j < 768; j += 256) orow[j] = 0;
      return;
    }
    xrow = X + (long)((bb * 64 + yy) * 64 + xx) * 768;
  } else {
    xrow = X + (long)p * 768;
  }
  float v0 = xrow[t], v1 = xrow[t + 256], v2 = xrow[t + 512];
  float s = v0 + v1 + v2, q = v0 * v0 + v1 * v1 + v2 * v2;
#pragma unroll
  for (int off = 32; off; off >>= 1){ s += __shfl_down(s, off); q += __shfl_down(q, off); }
  __shared__ float ps[4], pq[4], mv[2];
  int wid = t >> 6;
  if ((t & 63) == 0){ ps[wid] = s; pq[wid] = q; }
  __syncthreads();
  if (t == 0){
    float S = ps[0] + ps[1] + ps[2] + ps[3];
    float Q = pq[0] + pq[1] + pq[2] + pq[3];
    float mu = S * (1.0f / 768.0f);
    float var = Q * (1.0f / 768.0f) - mu * mu;
    mv[0] = mu; mv[1] = rsqrtf(var + 1e-5f);
  }
  __syncthreads();
  float mu = mv[0], rs = mv[1];
  orow[t]       = f2bf((v0 - mu) * rs * w[t]       + b[t]);
  orow[t + 256] = f2bf((v1 - mu) * rs * w[t + 256] + b[t + 256]);
  orow[t + 512] = f2bf((v2 - mu) * rs * w[t + 512] + b[t + 512]);
}

// ---------------- 128x128 tile GEMM, BK=32, 4 waves, 2-phase counted-vmcnt ----------
// 2 LDS buffers (32KB). stage(t+1) issued BEFORE compute(t); vmcnt(4) keeps
// tile-(t+1) loads in flight across compute + both barriers. No vmcnt(0) drain
// in the main loop.
// MODE 0: QKV -> scatter into per-head q/k panels + transposed v panel
// MODE 1: window->spatial scatter, + addsrc -> of32
// MODE 2: GELU -> bf16 [M][N]
// MODE 3: of32[idx] = v + addsrc[idx] (bias may be null)
template<int MODE>
__global__ __launch_bounds__(256, 5) void k_gemm(const unsigned short* __restrict__ A,
                                                 const unsigned short* __restrict__ Bt,
                                                 const float* bias,
                                                 unsigned short* obf,
                                                 float* of32,
                                                 const float* addsrc,
                                                 int M, int N, int K, int lda, int ldb,
                                                 int tilesN){
  __shared__ __align__(16) unsigned short lA[2 * 128 * 32];   // 16 KB
  __shared__ __align__(16) unsigned short lB[2 * 128 * 32];   // 16 KB
  int t = threadIdx.x;

  // bijective XCD swizzle (m204): contiguous wg chunk per XCD
  int nwg = gridDim.x, bid = blockIdx.x;
  int qq = nwg >> 3, rr = nwg & 7;
  int xcd = bid & 7, oo = bid >> 3;
  int wg = (xcd < rr ? xcd * (qq + 1) : rr * (qq + 1) + (xcd - rr) * qq) + oo;
  int tm = wg / tilesN, tn = wg % tilesN;

  int sl = (t & 3) ^ ((t >> 3) & 3);
  const unsigned short* ga[2]; const unsigned short* gb[2];
#pragma unroll
  for (int c2 = 0; c2 < 2; c2++){
    int i = tm * 128 + c2 * 64 + (t >> 2); if (i > M - 1) i = M - 1;
    ga[c2] = A + (long)i * lda + sl * 8;
    int n = tn * 128 + c2 * 64 + (t >> 2);
    gb[c2] = Bt + (long)n * ldb + sl * 8;
  }

  int lm = t & 15, lg = (t & 63) >> 4, wv = t >> 6;
  int wr = wv >> 1, wc = wv & 1;
  int laneoff = lm * 32 + ((lg ^ ((lm >> 1) & 3)) * 8);

  f32x4 acc[4][4];
#pragma unroll
  for (int a1 = 0; a1 < 4; a1++)
#pragma unroll
    for (int b1 = 0; b1 < 4; b1++) acc[a1][b1] = (f32x4){0.f, 0.f, 0.f, 0.f};

  const int nt = K >> 5;
  // prologue: stage tile 0 -> buffer 0
  {
    unsigned short* la = lA + t * 8;
    unsigned short* lb = lB + t * 8;
    gload16(ga[0], la);
    gload16(ga[1], la + 2048);
    gload16(gb[0], lb);
    gload16(gb[1], lb + 2048);
  }

  for (int tt = 0; tt < nt; tt++){
    int cur = tt & 1;
    if (tt + 1 < nt){
      int k0 = (tt + 1) << 5;
      unsigned short* la = lA + (cur ^ 1) * 4096 + t * 8;
      unsigned short* lb = lB + (cur ^ 1) * 4096 + t * 8;
      gload16(ga[0] + k0, la);
      gload16(ga[1] + k0, la + 2048);
      gload16(gb[0] + k0, lb);
      gload16(gb[1] + k0, lb + 2048);
      asm volatile("s_waitcnt vmcnt(4)" ::: "memory");   // tile tt landed; tt+1 in flight
    } else {
      asm volatile("s_waitcnt vmcnt(0)" ::: "memory");
    }
    __builtin_amdgcn_sched_barrier(0);
    __builtin_amdgcn_s_barrier();
    __builtin_amdgcn_sched_barrier(0);

    const unsigned short* lap = lA + cur * 4096;
    const unsigned short* lbp = lB + cur * 4096;
    bf16x8 af[4], bfr[4];
#pragma unroll
    for (int mi = 0; mi < 4; mi++)
      af[mi] = *(const bf16x8*)(lap + (wr * 64 + mi * 16) * 32 + laneoff);
#pragma unroll
    for (int ni = 0; ni < 4; ni++)
      bfr[ni] = *(const bf16x8*)(lbp + (wc * 64 + ni * 16) * 32 + laneoff);
    __builtin_amdgcn_s_setprio(1);
#pragma unroll
    for (int mi = 0; mi < 4; mi++)
#pragma unroll
      for (int ni = 0; ni < 4; ni++)
        acc[mi][ni] = __builtin_amdgcn_mfma_f32_16x16x32_bf16(af[mi], bfr[ni], acc[mi][ni], 0, 0, 0);
    __builtin_amdgcn_s_setprio(0);
    __builtin_amdgcn_sched_barrier(0);
    __builtin_amdgcn_s_barrier();     // buf[cur] now safe to overwrite next iter
  }

  int i0 = tm * 128 + wr * 64, j0 = tn * 128 + wc * 64;
#pragma unroll
  for (int mi = 0; mi < 4; mi++){
#pragma unroll
    for (int ni = 0; ni < 4; ni++){
      int jc = j0 + ni * 16 + lm;
      float bv = bias ? bias[jc] : 0.0f;
#pragma unroll
      for (int r = 0; r < 4; r++){
        int ir = i0 + mi * 16 + lg * 4 + r;
        float v = acc[mi][ni][r] + bv;
        if (MODE == 0){
          if (ir < M){
            int which = jc / 768, jj = jc - which * 768;
            int head = jj >> 6, cc = jj & 63;
            int win = ir / 196, tok = ir - win * 196;
            long wh = win * 12 + head;
            if (which == 0)      obf[Q_OFF + (wh * 196 + tok) * 64 + cc] = f2bf(v);
            else if (which == 1) obf[K_OFF + (wh * 196 + tok) * 64 + cc] = f2bf(v);
            else                 obf[VT_OFF + (wh * 64 + cc) * 200 + tok] = f2bf(v);
          }
        } else if (MODE == 1){
          if (ir < M){
            int win = ir / 196, tok = ir - win * 196;
            int bb = win / 25, wrem = win - bb * 25;
            int wy = wrem / 5, wx = wrem - wy * 5;
            int yy = wy * 14 + tok / 14, xx = wx * 14 + tok % 14;
            if (yy < 64 && xx < 64){
              long row = (long)((bb * 64 + yy) * 64 + xx);
              of32[row * 768 + jc] = v + addsrc[row * 768 + jc];
            }
          }
        } else if (MODE == 2){
          float g = 0.5f * v * (1.0f + erff(v * 0.70710678118654752f));
          obf[(long)ir * N + jc] = f2bf(g);
        } else {
          long idx = (long)ir * N + jc;
          of32[idx] = v + addsrc[idx];
        }
      }
    }
  }
}

// ---------------- fused window attention v4: K/Vt LDS-staged ----------------
#define KSW(r,c)  ((r) * 64 + ((c) ^ (((r) & 7) << 3)))
#define PSW(q,k)  ((q) * 32 + ((k) ^ (((q) & 3) << 3)))
#define DYN_ATTN  53760
__global__ __launch_bounds__(256, 2) void k_attn(const unsigned short* __restrict__ qb,
                                                 const unsigned short* __restrict__ kb,
                                                 const unsigned short* __restrict__ vtb,
                                                 const float* __restrict__ rph,
                                                 const float* __restrict__ rpw,
                                                 unsigned short* __restrict__ out){
  extern __shared__ __align__(16) char dynsm[];
  unsigned short* Ks = (unsigned short*)dynsm;              // 25,088 B
  unsigned short* Vt = (unsigned short*)(dynsm + 25088);    // 28,672 B  [64][224]
  __shared__ __align__(16) unsigned short Pscr[4][2][16 * 32];  // 8,192 B
  __shared__ unsigned short relhb[2744], relwb[2744];           // 10,976 B

  int t = threadIdx.x;
  int wh = blockIdx.x;
  int win = wh / 12, head = wh - win * 12;
  const unsigned short* qg  = qb  + (long)wh * 196 * 64;
  const unsigned short* kg  = kb  + (long)wh * 196 * 64;
  const unsigned short* vtg = vtb + (long)wh * 64 * 200;

  int lane = t & 63, wv = t >> 6;
  int lm = lane & 15, lg = lane >> 4;

  // ---- stage K (swizzled source -> linear LDS == swizzled layout) ----
  for (int ch = t; ch < 1568; ch += 256){
    int row = ch >> 3, c16 = ch & 7;
    gload16(kg + row * 64 + ((c16 ^ (row & 7)) << 3), (char*)Ks + ch * 16);
  }
  // ---- stage Vt linear [64][224]; cols 200..223 zero ----
  {
    int4 zero4 = {0, 0, 0, 0};
    for (int ch = t; ch < 1792; ch += 256){
      int row = ch / 28, c16 = ch - row * 28;
      if (c16 < 25) gload16(vtg + row * 200 + c16 * 8, (char*)Vt + ch * 16);
      else          *(int4*)((char*)Vt + ch * 16) = zero4;
    }
  }

  // ---- rel-pos tables via MFMA ----
  for (int ty = wv; ty < 14; ty += 4){
    {
      int qa = ty * 14 + lm; if (qa > 195) qa = 195;
      bf16x8 a0 = *(const bf16x8*)(&qg[qa * 64 + lg * 8]);
      bf16x8 a1 = *(const bf16x8*)(&qg[qa * 64 + 32 + lg * 8]);
      int ri = ty - lm + 13; ri = ri < 0 ? 0 : (ri > 26 ? 26 : ri);
      const float* bp = rph + ri * 64 + lg * 8;
      float4 c0 = *(const float4*)(bp),      c1 = *(const float4*)(bp + 4);
      float4 c2 = *(const float4*)(bp + 32), c3 = *(const float4*)(bp + 36);
      bf16x8 b0 = {(short)f2bf(c0.x),(short)f2bf(c0.y),(short)f2bf(c0.z),(short)f2bf(c0.w),
                   (short)f2bf(c1.x),(short)f2bf(c1.y),(short)f2bf(c1.z),(short)f2bf(c1.w)};
      bf16x8 b1 = {(short)f2bf(c2.x),(short)f2bf(c2.y),(short)f2bf(c2.z),(short)f2bf(c2.w),
                   (short)f2bf(c3.x),(short)f2bf(c3.y),(short)f2bf(c3.z),(short)f2bf(c3.w)};
      f32x4 d = (f32x4){0.f, 0.f, 0.f, 0.f};
      d = __builtin_amdgcn_mfma_f32_16x16x32_bf16(a0, b0, d, 0, 0, 0);
      d = __builtin_amdgcn_mfma_f32_16x16x32_bf16(a1, b1, d, 0, 0, 0);
#pragma unroll
      for (int r = 0; r < 4; r++){
        int txr = lg * 4 + r;
        if (txr < 14 && lm < 14) relhb[(ty * 14 + txr) * 14 + lm] = f2bf(d[r]);
      }
    }
    {
      int qa = lm * 14 + ty; if (qa > 195) qa = 195;
      bf16x8 a0 = *(const bf16x8*)(&qg[qa * 64 + lg * 8]);
      bf16x8 a1 = *(const bf16x8*)(&qg[qa * 64 + 32 + lg * 8]);
      int ri = ty - lm + 13; ri = ri < 0 ? 0 : (ri > 26 ? 26 : ri);
      const float* bp = rpw + ri * 64 + lg * 8;
      float4 c0 = *(const float4*)(bp),      c1 = *(const float4*)(bp + 4);
      float4 c2 = *(const float4*)(bp + 32), c3 = *(const float4*)(bp + 36);
      bf16x8 b0 = {(short)f2bf(c0.x),(short)f2bf(c0.y),(short)f2bf(c0.z),(short)f2bf(c0.w),
                   (short)f2bf(c1.x),(short)f2bf(c1.y),(short)f2bf(c1.z),(short)f2bf(c1.w)};
      bf16x8 b1 = {(short)f2bf(c2.x),(short)f2bf(c2.y),(short)f2bf(c2.z),(short)f2bf(c2.w),
                   (short)f2bf(c3.x),(short)f2bf(c3.y),(short)f2bf(c3.z),(short)f2bf(c3.w)};
      f32x4 d = (f32x4){0.f, 0.f, 0.f, 0.f};
      d = __builtin_amdgcn_mfma_f32_16x16x32_bf16(a0, b0, d, 0, 0, 0);
      d = __builtin_amdgcn_mfma_f32_16x16x32_bf16(a1, b1, d, 0, 0, 0);
#pragma unroll
      for (int r = 0; r < 4; r++){
        int tyr = lg * 4 + r;
        if (tyr < 14 && lm < 14) relwb[(tyr * 14 + ty) * 14 + lm] = f2bf(d[r]);
      }
    }
  }
  __syncthreads();

  int khw[13];
#pragma unroll
  for (int nt = 0; nt < 13; nt++){
    int kc = nt * 16 + lm;
    khw[nt] = (kc < 196) ? (((kc / 14) << 4) | (kc % 14)) : -1;
  }

  for (int mt = wv; mt < 13; mt += 4){
    int qr = mt * 16 + lm; if (qr > 195) qr = 195;
    bf16x8 aq0 = *(const bf16x8*)(&qg[qr * 64 + lg * 8]);
    bf16x8 aq1 = *(const bf16x8*)(&qg[qr * 64 + 32 + lg * 8]);
    f32x4 sacc[13];
#pragma unroll
    for (int nt = 0; nt < 13; nt++) sacc[nt] = (f32x4){0.f, 0.f, 0.f, 0.f};
#pragma unroll
    for (int nt = 0; nt < 13; nt++){
      int kr = nt * 16 + lm; if (kr > 195) kr = 195;
      bf16x8 bk0 = *(const bf16x8*)(&Ks[KSW(kr, lg * 8)]);
      bf16x8 bk1 = *(const bf16x8*)(&Ks[KSW(kr, 32 + lg * 8)]);
      sacc[nt] = __builtin_amdgcn_mfma_f32_16x16x32_bf16(aq0, bk0, sacc[nt], 0, 0, 0);
      sacc[nt] = __builtin_amdgcn_mfma_f32_16x16x32_bf16(aq1, bk1, sacc[nt], 0, 0, 0);
    }
    float rinv[4];
#pragma unroll
    for (int r = 0; r < 4; r++){
      int qrow = mt * 16 + lg * 4 + r;
      int qb14 = (qrow < 196) ? qrow * 14 : 0;
      float mx = -1e30f;
#pragma unroll
      for (int nt = 0; nt < 13; nt++){
        float s;
        if (khw[nt] >= 0)
          s = sacc[nt][r] * 0.125f + bf2f(relhb[qb14 + (khw[nt] >> 4)])
                                   + bf2f(relwb[qb14 + (khw[nt] & 15)]);
        else s = -1e30f;
        sacc[nt][r] = s; mx = fmaxf(mx, s);
      }
      mx = fmaxf(mx, __shfl_xor(mx, 1));
      mx = fmaxf(mx, __shfl_xor(mx, 2));
      mx = fmaxf(mx, __shfl_xor(mx, 4));
      mx = fmaxf(mx, __shfl_xor(mx, 8));
      float sum = 0.f;
#pragma unroll
      for (int nt = 0; nt < 13; nt++){
        float p = __expf(sacc[nt][r] - mx);
        sum += p;
        sacc[nt][r] = p;
      }
      sum += __shfl_xor(sum, 1); sum += __shfl_xor(sum, 2);
      sum += __shfl_xor(sum, 4); sum += __shfl_xor(sum, 8);
      rinv[r] = 1.0f / sum;
    }
    f32x4 oacc[4];
#pragma unroll
    for (int vt = 0; vt < 4; vt++) oacc[vt] = (f32x4){0.f, 0.f, 0.f, 0.f};
#pragma unroll
    for (int kk = 0; kk < 7; kk++){
      unsigned short* Ps = &Pscr[wv][kk & 1][0];
      int nt0 = 2 * kk, nt1 = 2 * kk + 1;
#pragma unroll
      for (int r = 0; r < 4; r++){
        int q = lg * 4 + r;
        Ps[PSW(q, lm)]      = f2bf(sacc[nt0][r]);
        Ps[PSW(q, lm + 16)] = (nt1 < 13) ? f2bf(sacc[nt1][r]) : (unsigned short)0;
      }
      bf16x8 ap = *(const bf16x8*)(&Ps[PSW(lm, lg * 8)]);
#pragma unroll
      for (int vt = 0; vt < 4; vt++){
        bf16x8 bv = *(const bf16x8*)(&Vt[(vt * 16 + lm) * 224 + kk * 32 + lg * 8]);
        oacc[vt] = __builtin_amdgcn_mfma_f32_16x16x32_bf16(ap, bv, oacc[vt], 0, 0, 0);
      }
    }
#pragma unroll
    for (int vt = 0; vt < 4; vt++){
#pragma unroll
      for (int r = 0; r < 4; r++){
        int orow = mt * 16 + lg * 4 + r;
        if (orow < 196)
          out[(long)(win * 196 + orow) * 768 + head * 64 + vt * 16 + lm] =
              f2bf(oacc[vt][r] * rinv[r]);
      }
    }
  }
}

// ---------------- workspace layout ----------------
static const long O_W     = 60211200;
static const long O_PROJT = 63750144;
static const long O_L1T   = 64929792;
static const long O_L2T   = 69648384;
static const long O_R2    = 74366976;
static const unsigned long WS_FULL = 275693568UL;

extern "C" void kernel_launch(void* const* d_in, const int* in_sizes, int n_in,
                              void* d_out, int out_size, void* d_ws, size_t ws_size,
                              hipStream_t stream){
  const float* x     = (const float*)d_in[0];
  const float* n1w   = (const float*)d_in[1];
  const float* n1b   = (const float*)d_in[2];
  const float* qkvw  = (const float*)d_in[3];
  const float* qkvb  = (const float*)d_in[4];
  const float* projw = (const float*)d_in[5];
  const float* projb = (const float*)d_in[6];
  const float* rph   = (const float*)d_in[7];
  const float* rpw   = (const float*)d_in[8];
  const float* n2w   = (const float*)d_in[9];
  const float* n2b   = (const float*)d_in[10];
  const float* l1w   = (const float*)d_in[11];
  const float* l1b   = (const float*)d_in[12];
  const float* l2w   = (const float*)d_in[13];
  const float* l2b   = (const float*)d_in[14];
  float* out = (float*)d_out;
  char* ws = (char*)d_ws;

  unsigned short* hpad   = (unsigned short*)(ws);            // R0
  unsigned short* attout = (unsigned short*)(ws);            // R0
  unsigned short* h2     = (unsigned short*)(ws);            // R0
  unsigned short* wqkvT  = (unsigned short*)(ws + O_W);
  unsigned short* wprojT = (unsigned short*)(ws + O_PROJT);
  unsigned short* wl1T   = (unsigned short*)(ws + O_L1T);
  unsigned short* wl2T   = (unsigned short*)(ws + O_L2T);
  unsigned short* r2     = (unsigned short*)(ws + O_R2);
  unsigned short* hidden = (unsigned short*)(ws + O_R2);     // reuse after attention

  const unsigned short* vtbuf = r2 + VT_OFF;
  const unsigned short* qbuf  = r2 + Q_OFF;
  const unsigned short* kbuf  = r2 + K_OFF;

  const bool full = (ws_size >= WS_FULL);

  // weight casts
  k_castT<<<(768 / 32) * (2304 / 32), 256, 0, stream>>>(qkvw, wqkvT, 768, 2304);
  k_castT<<<(768 / 32) * (768 / 32),  256, 0, stream>>>(projw, wprojT, 768, 768);
  k_castT<<<(768 / 32) * (3072 / 32), 256, 0, stream>>>(l1w, wl1T, 768, 3072);
  k_castT<<<(3072 / 32) * (768 / 32), 256, 0, stream>>>(l2w, wl2T, 3072, 768);

  // LN1 -> window-ordered padded bf16 [39200][768]
  k_ln<<<39200, 256, 0, stream>>>(x, n1w, n1b, hpad, 1);

  // QKV GEMM -> per-head q/k panels + transposed v panel
  k_gemm<0><<<307 * 18, 256, 0, stream>>>(hpad, wqkvT, qkvb, r2, nullptr, nullptr,
                                          39200, 2304, 768, 768, 768, 18);

  // fused window attention -> attout bf16 [39200][768]
  (void)hipFuncSetAttribute((const void*)k_attn,
                            hipFuncAttributeMaxDynamicSharedMemorySize, DYN_ATTN);
  k_attn<<<2400, 256, DYN_ATTN, stream>>>(qbuf, kbuf, vtbuf, rph, rpw, attout);

  // proj + unpartition + residual -> y in d_out (fp32)
  k_gemm<1><<<307 * 6, 256, 0, stream>>>(attout, wprojT, projb, nullptr, out, x,
                                         39200, 768, 768, 768, 768, 6);

  // LN2 (reads y from d_out) -> h2 bf16 [32768][768]
  k_ln<<<32768, 256, 0, stream>>>(out, n2w, n2b, h2, 0);

  if (full){
    k_gemm<2><<<256 * 24, 256, 0, stream>>>(h2, wl1T, l1b, hidden, nullptr, nullptr,
                                            32768, 3072, 768, 768, 768, 24);
    k_gemm<3><<<256 * 6, 256, 0, stream>>>(hidden, wl2T, l2b, nullptr, out, out,
                                           32768, 768, 3072, 3072, 3072, 6);
  } else {
    for (int c = 0; c < 2; c++){
      k_gemm<2><<<256 * 12, 256, 0, stream>>>(h2, wl1T + (long)c * 1536 * 768,
                                              l1b + c * 1536, hidden, nullptr, nullptr,
                                              32768, 1536, 768, 768, 768, 12);
      k_gemm<3><<<256 * 6, 256, 0, stream>>>(hidden, wl2T + c * 1536,
                                             c == 0 ? l2b : nullptr, nullptr, out, out,
                                             32768, 768, 1536, 1536, 3072, 6);
    }
  }
}

// Round 8
// 1312.168 us; speedup vs baseline: 2.4000x; 2.4000x over previous
//
#include <hip/hip_runtime.h>
#include <hip/hip_bf16.h>
#include <stdint.h>

typedef __attribute__((ext_vector_type(8))) short bf16x8;
typedef __attribute__((ext_vector_type(4))) float f32x4;

__device__ __forceinline__ float bf2f(unsigned short u){
  union { unsigned int i; float f; } v; v.i = ((unsigned int)u) << 16; return v.f;
}
__device__ __forceinline__ unsigned short f2bf(float f){
  union { float f; unsigned int i; } v; v.f = f;
  return (unsigned short)((v.i + 0x7FFFu + ((v.i >> 16) & 1u)) >> 16);
}

__device__ __forceinline__ void gload16(const void* g, void* l){
  __builtin_amdgcn_global_load_lds(
      (const __attribute__((address_space(1))) void*)g,
      (__attribute__((address_space(3))) void*)l, 16, 0, 0);
}

// per-head panel offsets inside R2 (in shorts)
#define VT_OFF 0L
#define Q_OFF  30720000L
#define K_OFF  60825600L

// ---------------- weight cast + transpose: W[K][N] f32 -> Wt[N][K] bf16 ----------------
__global__ __launch_bounds__(256) void k_castT(const float* __restrict__ W,
                                               unsigned short* __restrict__ Wt,
                                               int K, int N){
  __shared__ float tl[32][33];
  int ntn = N >> 5;
  int kt = blockIdx.x / ntn, nt = blockIdx.x % ntn;
  int r = threadIdx.x >> 5, c = threadIdx.x & 31;
#pragma unroll
  for (int rr = 0; rr < 4; rr++){
    int row = (kt << 5) + r + (rr << 3);
    tl[r + (rr << 3)][c] = W[(long)row * N + (nt << 5) + c];
  }
  __syncthreads();
#pragma unroll
  for (int rr = 0; rr < 4; rr++){
    int n = (nt << 5) + r + (rr << 3);
    int k = (kt << 5) + c;
    Wt[(long)n * K + k] = f2bf(tl[c][r + (rr << 3)]);
  }
}

// ---------------- LayerNorm fp32 -> bf16 ----------------
__global__ __launch_bounds__(256) void k_ln(const float* __restrict__ X,
                                            const float* __restrict__ w,
                                            const float* __restrict__ b,
                                            unsigned short* __restrict__ out,
                                            int mode){
  int p = blockIdx.x, t = threadIdx.x;
  unsigned short* orow = out + (long)p * 768;
  const float* xrow;
  if (mode == 1){
    int win = p / 196, tok = p - win * 196;
    int bb = win / 25, wrem = win - bb * 25;
    int wy = wrem / 5, wx = wrem - wy * 5;
    int ty = tok / 14, tx = tok - ty * 14;
    int yy = wy * 14 + ty, xx = wx * 14 + tx;
    if (yy >= 64 || xx >= 64){
      for (int j = t; j < 768; j += 256) orow[j] = 0;
      return;
    }
    xrow = X + (long)((bb * 64 + yy) * 64 + xx) * 768;
  } else {
    xrow = X + (long)p * 768;
  }
  float v0 = xrow[t], v1 = xrow[t + 256], v2 = xrow[t + 512];
  float s = v0 + v1 + v2, q = v0 * v0 + v1 * v1 + v2 * v2;
#pragma unroll
  for (int off = 32; off; off >>= 1){ s += __shfl_down(s, off); q += __shfl_down(q, off); }
  __shared__ float ps[4], pq[4], mv[2];
  int wid = t >> 6;
  if ((t & 63) == 0){ ps[wid] = s; pq[wid] = q; }
  __syncthreads();
  if (t == 0){
    float S = ps[0] + ps[1] + ps[2] + ps[3];
    float Q = pq[0] + pq[1] + pq[2] + pq[3];
    float mu = S * (1.0f / 768.0f);
    float var = Q * (1.0f / 768.0f) - mu * mu;
    mv[0] = mu; mv[1] = rsqrtf(var + 1e-5f);
  }
  __syncthreads();
  float mu = mv[0], rs = mv[1];
  orow[t]       = f2bf((v0 - mu) * rs * w[t]       + b[t]);
  orow[t + 256] = f2bf((v1 - mu) * rs * w[t + 256] + b[t + 256]);
  orow[t + 512] = f2bf((v2 - mu) * rs * w[t + 512] + b[t + 512]);
}

// ---------------- 128x128 tile GEMM, BK=32, 4 waves, 2-phase counted-vmcnt ----------
// 2 LDS buffers (32KB). stage(t+1) issued BEFORE compute(t); vmcnt(4) keeps
// tile-(t+1) loads in flight across compute + both barriers. No vmcnt(0) drain
// in the main loop. Plain launch bounds: do NOT cap VGPR (acc[4][4] = 64 regs;
// capping to 5 waves/SIMD spilled it to scratch in r7 -> 2.6GB writes).
// MODE 0: QKV -> scatter into per-head q/k panels + transposed v panel
// MODE 1: window->spatial scatter, + addsrc -> of32
// MODE 2: GELU -> bf16 [M][N]
// MODE 3: of32[idx] = v + addsrc[idx] (bias may be null)
template<int MODE>
__global__ __launch_bounds__(256) void k_gemm(const unsigned short* __restrict__ A,
                                              const unsigned short* __restrict__ Bt,
                                              const float* bias,
                                              unsigned short* obf,
                                              float* of32,
                                              const float* addsrc,
                                              int M, int N, int K, int lda, int ldb,
                                              int tilesN){
  __shared__ __align__(16) unsigned short lA[2 * 128 * 32];   // 16 KB
  __shared__ __align__(16) unsigned short lB[2 * 128 * 32];   // 16 KB
  int t = threadIdx.x;

  // bijective XCD swizzle (m204): contiguous wg chunk per XCD
  int nwg = gridDim.x, bid = blockIdx.x;
  int qq = nwg >> 3, rr = nwg & 7;
  int xcd = bid & 7, oo = bid >> 3;
  int wg = (xcd < rr ? xcd * (qq + 1) : rr * (qq + 1) + (xcd - rr) * qq) + oo;
  int tm = wg / tilesN, tn = wg % tilesN;

  int sl = (t & 3) ^ ((t >> 3) & 3);
  const unsigned short* ga[2]; const unsigned short* gb[2];
#pragma unroll
  for (int c2 = 0; c2 < 2; c2++){
    int i = tm * 128 + c2 * 64 + (t >> 2); if (i > M - 1) i = M - 1;
    ga[c2] = A + (long)i * lda + sl * 8;
    int n = tn * 128 + c2 * 64 + (t >> 2);
    gb[c2] = Bt + (long)n * ldb + sl * 8;
  }

  int lm = t & 15, lg = (t & 63) >> 4, wv = t >> 6;
  int wr = wv >> 1, wc = wv & 1;
  int laneoff = lm * 32 + ((lg ^ ((lm >> 1) & 3)) * 8);

  f32x4 acc[4][4];
#pragma unroll
  for (int a1 = 0; a1 < 4; a1++)
#pragma unroll
    for (int b1 = 0; b1 < 4; b1++) acc[a1][b1] = (f32x4){0.f, 0.f, 0.f, 0.f};

  const int nt = K >> 5;
  // prologue: stage tile 0 -> buffer 0
  {
    unsigned short* la = lA + t * 8;
    unsigned short* lb = lB + t * 8;
    gload16(ga[0], la);
    gload16(ga[1], la + 2048);
    gload16(gb[0], lb);
    gload16(gb[1], lb + 2048);
  }

  for (int tt = 0; tt < nt; tt++){
    int cur = tt & 1;
    if (tt + 1 < nt){
      int k0 = (tt + 1) << 5;
      unsigned short* la = lA + (cur ^ 1) * 4096 + t * 8;
      unsigned short* lb = lB + (cur ^ 1) * 4096 + t * 8;
      gload16(ga[0] + k0, la);
      gload16(ga[1] + k0, la + 2048);
      gload16(gb[0] + k0, lb);
      gload16(gb[1] + k0, lb + 2048);
      asm volatile("s_waitcnt vmcnt(4)" ::: "memory");   // tile tt landed; tt+1 in flight
    } else {
      asm volatile("s_waitcnt vmcnt(0)" ::: "memory");
    }
    __builtin_amdgcn_sched_barrier(0);
    __builtin_amdgcn_s_barrier();
    __builtin_amdgcn_sched_barrier(0);

    const unsigned short* lap = lA + cur * 4096;
    const unsigned short* lbp = lB + cur * 4096;
    bf16x8 af[4], bfr[4];
#pragma unroll
    for (int mi = 0; mi < 4; mi++)
      af[mi] = *(const bf16x8*)(lap + (wr * 64 + mi * 16) * 32 + laneoff);
#pragma unroll
    for (int ni = 0; ni < 4; ni++)
      bfr[ni] = *(const bf16x8*)(lbp + (wc * 64 + ni * 16) * 32 + laneoff);
    __builtin_amdgcn_s_setprio(1);
#pragma unroll
    for (int mi = 0; mi < 4; mi++)
#pragma unroll
      for (int ni = 0; ni < 4; ni++)
        acc[mi][ni] = __builtin_amdgcn_mfma_f32_16x16x32_bf16(af[mi], bfr[ni], acc[mi][ni], 0, 0, 0);
    __builtin_amdgcn_s_setprio(0);
    __builtin_amdgcn_sched_barrier(0);
    __builtin_amdgcn_s_barrier();     // buf[cur] now safe to overwrite next iter
  }

  int i0 = tm * 128 + wr * 64, j0 = tn * 128 + wc * 64;
#pragma unroll
  for (int mi = 0; mi < 4; mi++){
#pragma unroll
    for (int ni = 0; ni < 4; ni++){
      int jc = j0 + ni * 16 + lm;
      float bv = bias ? bias[jc] : 0.0f;
#pragma unroll
      for (int r = 0; r < 4; r++){
        int ir = i0 + mi * 16 + lg * 4 + r;
        float v = acc[mi][ni][r] + bv;
        if (MODE == 0){
          if (ir < M){
            int which = jc / 768, jj = jc - which * 768;
            int head = jj >> 6, cc = jj & 63;
            int win = ir / 196, tok = ir - win * 196;
            long wh = win * 12 + head;
            if (which == 0)      obf[Q_OFF + (wh * 196 + tok) * 64 + cc] = f2bf(v);
            else if (which == 1) obf[K_OFF + (wh * 196 + tok) * 64 + cc] = f2bf(v);
            else                 obf[VT_OFF + (wh * 64 + cc) * 200 + tok] = f2bf(v);
          }
        } else if (MODE == 1){
          if (ir < M){
            int win = ir / 196, tok = ir - win * 196;
            int bb = win / 25, wrem = win - bb * 25;
            int wy = wrem / 5, wx = wrem - wy * 5;
            int yy = wy * 14 + tok / 14, xx = wx * 14 + tok % 14;
            if (yy < 64 && xx < 64){
              long row = (long)((bb * 64 + yy) * 64 + xx);
              of32[row * 768 + jc] = v + addsrc[row * 768 + jc];
            }
          }
        } else if (MODE == 2){
          float g = 0.5f * v * (1.0f + erff(v * 0.70710678118654752f));
          obf[(long)ir * N + jc] = f2bf(g);
        } else {
          long idx = (long)ir * N + jc;
          of32[idx] = v + addsrc[idx];
        }
      }
    }
  }
}

// ---------------- fused window attention v4: K/Vt LDS-staged ----------------
#define KSW(r,c)  ((r) * 64 + ((c) ^ (((r) & 7) << 3)))
#define PSW(q,k)  ((q) * 32 + ((k) ^ (((q) & 3) << 3)))
#define DYN_ATTN  53760
__global__ __launch_bounds__(256, 2) void k_attn(const unsigned short* __restrict__ qb,
                                                 const unsigned short* __restrict__ kb,
                                                 const unsigned short* __restrict__ vtb,
                                                 const float* __restrict__ rph,
                                                 const float* __restrict__ rpw,
                                                 unsigned short* __restrict__ out){
  extern __shared__ __align__(16) char dynsm[];
  unsigned short* Ks = (unsigned short*)dynsm;              // 25,088 B
  unsigned short* Vt = (unsigned short*)(dynsm + 25088);    // 28,672 B  [64][224]
  __shared__ __align__(16) unsigned short Pscr[4][2][16 * 32];  // 8,192 B
  __shared__ unsigned short relhb[2744], relwb[2744];           // 10,976 B

  int t = threadIdx.x;
  int wh = blockIdx.x;
  int win = wh / 12, head = wh - win * 12;
  const unsigned short* qg  = qb  + (long)wh * 196 * 64;
  const unsigned short* kg  = kb  + (long)wh * 196 * 64;
  const unsigned short* vtg = vtb + (long)wh * 64 * 200;

  int lane = t & 63, wv = t >> 6;
  int lm = lane & 15, lg = lane >> 4;

  // ---- stage K (swizzled source -> linear LDS == swizzled layout) ----
  for (int ch = t; ch < 1568; ch += 256){
    int row = ch >> 3, c16 = ch & 7;
    gload16(kg + row * 64 + ((c16 ^ (row & 7)) << 3), (char*)Ks + ch * 16);
  }
  // ---- stage Vt linear [64][224]; cols 200..223 zero ----
  {
    int4 zero4 = {0, 0, 0, 0};
    for (int ch = t; ch < 1792; ch += 256){
      int row = ch / 28, c16 = ch - row * 28;
      if (c16 < 25) gload16(vtg + row * 200 + c16 * 8, (char*)Vt + ch * 16);
      else          *(int4*)((char*)Vt + ch * 16) = zero4;
    }
  }

  // ---- rel-pos tables via MFMA ----
  for (int ty = wv; ty < 14; ty += 4){
    {
      int qa = ty * 14 + lm; if (qa > 195) qa = 195;
      bf16x8 a0 = *(const bf16x8*)(&qg[qa * 64 + lg * 8]);
      bf16x8 a1 = *(const bf16x8*)(&qg[qa * 64 + 32 + lg * 8]);
      int ri = ty - lm + 13; ri = ri < 0 ? 0 : (ri > 26 ? 26 : ri);
      const float* bp = rph + ri * 64 + lg * 8;
      float4 c0 = *(const float4*)(bp),      c1 = *(const float4*)(bp + 4);
      float4 c2 = *(const float4*)(bp + 32), c3 = *(const float4*)(bp + 36);
      bf16x8 b0 = {(short)f2bf(c0.x),(short)f2bf(c0.y),(short)f2bf(c0.z),(short)f2bf(c0.w),
                   (short)f2bf(c1.x),(short)f2bf(c1.y),(short)f2bf(c1.z),(short)f2bf(c1.w)};
      bf16x8 b1 = {(short)f2bf(c2.x),(short)f2bf(c2.y),(short)f2bf(c2.z),(short)f2bf(c2.w),
                   (short)f2bf(c3.x),(short)f2bf(c3.y),(short)f2bf(c3.z),(short)f2bf(c3.w)};
      f32x4 d = (f32x4){0.f, 0.f, 0.f, 0.f};
      d = __builtin_amdgcn_mfma_f32_16x16x32_bf16(a0, b0, d, 0, 0, 0);
      d = __builtin_amdgcn_mfma_f32_16x16x32_bf16(a1, b1, d, 0, 0, 0);
#pragma unroll
      for (int r = 0; r < 4; r++){
        int txr = lg * 4 + r;
        if (txr < 14 && lm < 14) relhb[(ty * 14 + txr) * 14 + lm] = f2bf(d[r]);
      }
    }
    {
      int qa = lm * 14 + ty; if (qa > 195) qa = 195;
      bf16x8 a0 = *(const bf16x8*)(&qg[qa * 64 + lg * 8]);
      bf16x8 a1 = *(const bf16x8*)(&qg[qa * 64 + 32 + lg * 8]);
      int ri = ty - lm + 13; ri = ri < 0 ? 0 : (ri > 26 ? 26 : ri);
      const float* bp = rpw + ri * 64 + lg * 8;
      float4 c0 = *(const float4*)(bp),      c1 = *(const float4*)(bp + 4);
      float4 c2 = *(const float4*)(bp + 32), c3 = *(const float4*)(bp + 36);
      bf16x8 b0 = {(short)f2bf(c0.x),(short)f2bf(c0.y),(short)f2bf(c0.z),(short)f2bf(c0.w),
                   (short)f2bf(c1.x),(short)f2bf(c1.y),(short)f2bf(c1.z),(short)f2bf(c1.w)};
      bf16x8 b1 = {(short)f2bf(c2.x),(short)f2bf(c2.y),(short)f2bf(c2.z),(short)f2bf(c2.w),
                   (short)f2bf(c3.x),(short)f2bf(c3.y),(short)f2bf(c3.z),(short)f2bf(c3.w)};
      f32x4 d = (f32x4){0.f, 0.f, 0.f, 0.f};
      d = __builtin_amdgcn_mfma_f32_16x16x32_bf16(a0, b0, d, 0, 0, 0);
      d = __builtin_amdgcn_mfma_f32_16x16x32_bf16(a1, b1, d, 0, 0, 0);
#pragma unroll
      for (int r = 0; r < 4; r++){
        int tyr = lg * 4 + r;
        if (tyr < 14 && lm < 14) relwb[(tyr * 14 + ty) * 14 + lm] = f2bf(d[r]);
      }
    }
  }
  __syncthreads();

  int khw[13];
#pragma unroll
  for (int nt = 0; nt < 13; nt++){
    int kc = nt * 16 + lm;
    khw[nt] = (kc < 196) ? (((kc / 14) << 4) | (kc % 14)) : -1;
  }

  for (int mt = wv; mt < 13; mt += 4){
    int qr = mt * 16 + lm; if (qr > 195) qr = 195;
    bf16x8 aq0 = *(const bf16x8*)(&qg[qr * 64 + lg * 8]);
    bf16x8 aq1 = *(const bf16x8*)(&qg[qr * 64 + 32 + lg * 8]);
    f32x4 sacc[13];
#pragma unroll
    for (int nt = 0; nt < 13; nt++) sacc[nt] = (f32x4){0.f, 0.f, 0.f, 0.f};
#pragma unroll
    for (int nt = 0; nt < 13; nt++){
      int kr = nt * 16 + lm; if (kr > 195) kr = 195;
      bf16x8 bk0 = *(const bf16x8*)(&Ks[KSW(kr, lg * 8)]);
      bf16x8 bk1 = *(const bf16x8*)(&Ks[KSW(kr, 32 + lg * 8)]);
      sacc[nt] = __builtin_amdgcn_mfma_f32_16x16x32_bf16(aq0, bk0, sacc[nt], 0, 0, 0);
      sacc[nt] = __builtin_amdgcn_mfma_f32_16x16x32_bf16(aq1, bk1, sacc[nt], 0, 0, 0);
    }
    float rinv[4];
#pragma unroll
    for (int r = 0; r < 4; r++){
      int qrow = mt * 16 + lg * 4 + r;
      int qb14 = (qrow < 196) ? qrow * 14 : 0;
      float mx = -1e30f;
#pragma unroll
      for (int nt = 0; nt < 13; nt++){
        float s;
        if (khw[nt] >= 0)
          s = sacc[nt][r] * 0.125f + bf2f(relhb[qb14 + (khw[nt] >> 4)])
                                   + bf2f(relwb[qb14 + (khw[nt] & 15)]);
        else s = -1e30f;
        sacc[nt][r] = s; mx = fmaxf(mx, s);
      }
      mx = fmaxf(mx, __shfl_xor(mx, 1));
      mx = fmaxf(mx, __shfl_xor(mx, 2));
      mx = fmaxf(mx, __shfl_xor(mx, 4));
      mx = fmaxf(mx, __shfl_xor(mx, 8));
      float sum = 0.f;
#pragma unroll
      for (int nt = 0; nt < 13; nt++){
        float p = __expf(sacc[nt][r] - mx);
        sum += p;
        sacc[nt][r] = p;
      }
      sum += __shfl_xor(sum, 1); sum += __shfl_xor(sum, 2);
      sum += __shfl_xor(sum, 4); sum += __shfl_xor(sum, 8);
      rinv[r] = 1.0f / sum;
    }
    f32x4 oacc[4];
#pragma unroll
    for (int vt = 0; vt < 4; vt++) oacc[vt] = (f32x4){0.f, 0.f, 0.f, 0.f};
#pragma unroll
    for (int kk = 0; kk < 7; kk++){
      unsigned short* Ps = &Pscr[wv][kk & 1][0];
      int nt0 = 2 * kk, nt1 = 2 * kk + 1;
#pragma unroll
      for (int r = 0; r < 4; r++){
        int q = lg * 4 + r;
        Ps[PSW(q, lm)]      = f2bf(sacc[nt0][r]);
        Ps[PSW(q, lm + 16)] = (nt1 < 13) ? f2bf(sacc[nt1][r]) : (unsigned short)0;
      }
      bf16x8 ap = *(const bf16x8*)(&Ps[PSW(lm, lg * 8)]);
#pragma unroll
      for (int vt = 0; vt < 4; vt++){
        bf16x8 bv = *(const bf16x8*)(&Vt[(vt * 16 + lm) * 224 + kk * 32 + lg * 8]);
        oacc[vt] = __builtin_amdgcn_mfma_f32_16x16x32_bf16(ap, bv, oacc[vt], 0, 0, 0);
      }
    }
#pragma unroll
    for (int vt = 0; vt < 4; vt++){
#pragma unroll
      for (int r = 0; r < 4; r++){
        int orow = mt * 16 + lg * 4 + r;
        if (orow < 196)
          out[(long)(win * 196 + orow) * 768 + head * 64 + vt * 16 + lm] =
              f2bf(oacc[vt][r] * rinv[r]);
      }
    }
  }
}

// ---------------- workspace layout ----------------
static const long O_W     = 60211200;
static const long O_PROJT = 63750144;
static const long O_L1T   = 64929792;
static const long O_L2T   = 69648384;
static const long O_R2    = 74366976;
static const unsigned long WS_FULL = 275693568UL;

extern "C" void kernel_launch(void* const* d_in, const int* in_sizes, int n_in,
                              void* d_out, int out_size, void* d_ws, size_t ws_size,
                              hipStream_t stream){
  const float* x     = (const float*)d_in[0];
  const float* n1w   = (const float*)d_in[1];
  const float* n1b   = (const float*)d_in[2];
  const float* qkvw  = (const float*)d_in[3];
  const float* qkvb  = (const float*)d_in[4];
  const float* projw = (const float*)d_in[5];
  const float* projb = (const float*)d_in[6];
  const float* rph   = (const float*)d_in[7];
  const float* rpw   = (const float*)d_in[8];
  const float* n2w   = (const float*)d_in[9];
  const float* n2b   = (const float*)d_in[10];
  const float* l1w   = (const float*)d_in[11];
  const float* l1b   = (const float*)d_in[12];
  const float* l2w   = (const float*)d_in[13];
  const float* l2b   = (const float*)d_in[14];
  float* out = (float*)d_out;
  char* ws = (char*)d_ws;

  unsigned short* hpad   = (unsigned short*)(ws);            // R0
  unsigned short* attout = (unsigned short*)(ws);            // R0
  unsigned short* h2     = (unsigned short*)(ws);            // R0
  unsigned short* wqkvT  = (unsigned short*)(ws + O_W);
  unsigned short* wprojT = (unsigned short*)(ws + O_PROJT);
  unsigned short* wl1T   = (unsigned short*)(ws + O_L1T);
  unsigned short* wl2T   = (unsigned short*)(ws + O_L2T);
  unsigned short* r2     = (unsigned short*)(ws + O_R2);
  unsigned short* hidden = (unsigned short*)(ws + O_R2);     // reuse after attention

  const unsigned short* vtbuf = r2 + VT_OFF;
  const unsigned short* qbuf  = r2 + Q_OFF;
  const unsigned short* kbuf  = r2 + K_OFF;

  const bool full = (ws_size >= WS_FULL);

  // weight casts
  k_castT<<<(768 / 32) * (2304 / 32), 256, 0, stream>>>(qkvw, wqkvT, 768, 2304);
  k_castT<<<(768 / 32) * (768 / 32),  256, 0, stream>>>(projw, wprojT, 768, 768);
  k_castT<<<(768 / 32) * (3072 / 32), 256, 0, stream>>>(l1w, wl1T, 768, 3072);
  k_castT<<<(3072 / 32) * (768 / 32), 256, 0, stream>>>(l2w, wl2T, 3072, 768);

  // LN1 -> window-ordered padded bf16 [39200][768]
  k_ln<<<39200, 256, 0, stream>>>(x, n1w, n1b, hpad, 1);

  // QKV GEMM -> per-head q/k panels + transposed v panel
  k_gemm<0><<<307 * 18, 256, 0, stream>>>(hpad, wqkvT, qkvb, r2, nullptr, nullptr,
                                          39200, 2304, 768, 768, 768, 18);

  // fused window attention -> attout bf16 [39200][768]
  (void)hipFuncSetAttribute((const void*)k_attn,
                            hipFuncAttributeMaxDynamicSharedMemorySize, DYN_ATTN);
  k_attn<<<2400, 256, DYN_ATTN, stream>>>(qbuf, kbuf, vtbuf, rph, rpw, attout);

  // proj + unpartition + residual -> y in d_out (fp32)
  k_gemm<1><<<307 * 6, 256, 0, stream>>>(attout, wprojT, projb, nullptr, out, x,
                                         39200, 768, 768, 768, 768, 6);

  // LN2 (reads y from d_out) -> h2 bf16 [32768][768]
  k_ln<<<32768, 256, 0, stream>>>(out, n2w, n2b, h2, 0);

  if (full){
    k_gemm<2><<<256 * 24, 256, 0, stream>>>(h2, wl1T, l1b, hidden, nullptr, nullptr,
                                            32768, 3072, 768, 768, 768, 24);
    k_gemm<3><<<256 * 6, 256, 0, stream>>>(hidden, wl2T, l2b, nullptr, out, out,
                                           32768, 768, 3072, 3072, 3072, 6);
  } else {
    for (int c = 0; c < 2; c++){
      k_gemm<2><<<256 * 12, 256, 0, stream>>>(h2, wl1T + (long)c * 1536 * 768,
                                              l1b + c * 1536, hidden, nullptr, nullptr,
                                              32768, 1536, 768, 768, 768, 12);
      k_gemm<3><<<256 * 6, 256, 0, stream>>>(hidden, wl2T + c * 1536,
                                             c == 0 ? l2b : nullptr, nullptr, out, out,
                                             32768, 768, 1536, 1536, 3072, 6);
    }
  }
}